// Round 1
// 596.946 us; speedup vs baseline: 1.1845x; 1.1845x over previous
//
#include <hip/hip_runtime.h>
#include <hip/hip_bf16.h>
#include <cstddef>
#include <cstdint>

#define NB 8
#define LQ 8192
#define DMODEL 256
#define NHD 8
#define NLV 4
#define NPT 4
#define LEN_IN 19560          // 92*160 + 46*80 + 23*40 + 12*20
#define NQ (NB * LQ)          // 65536
#define MV (NB * LEN_IN)      // 156480
#define MVP 156544            // MV padded to multiple of 128 (1223*128)

using bf16x8 = __attribute__((ext_vector_type(8))) short;
using f32x4  = __attribute__((ext_vector_type(4))) float;

typedef const __attribute__((address_space(1))) void* gas_ptr;
typedef __attribute__((address_space(3))) void* las_ptr;

__device__ __forceinline__ void gl_lds16(const void* g, void* l) {
  __builtin_amdgcn_global_load_lds((gas_ptr)g, (las_ptr)l, 16, 0, 0);
}
__device__ __forceinline__ float bflo(unsigned u) {
  union { unsigned i; float f; } c; c.i = u << 16; return c.f;
}
__device__ __forceinline__ float bfhi(unsigned u) {
  union { unsigned i; float f; } c; c.i = u & 0xffff0000u; return c.f;
}

// ---------------------------------------------------------------------------
// fp32 -> bf16 row-major convert with zero-padded tail rows.
// ---------------------------------------------------------------------------
__global__ __launch_bounds__(256) void convert_bf16_pad(
    const float* __restrict__ src, __hip_bfloat16* __restrict__ dst,
    long src_elems) {
  const long idx8 = (long)(blockIdx.x * 256 + threadIdx.x) * 8;
  ushort4 o0, o1;
  if (idx8 < src_elems) {
    float4 f0 = *(const float4*)(src + idx8);
    float4 f1 = *(const float4*)(src + idx8 + 4);
    o0 = {__bfloat16_as_ushort(__float2bfloat16(f0.x)),
          __bfloat16_as_ushort(__float2bfloat16(f0.y)),
          __bfloat16_as_ushort(__float2bfloat16(f0.z)),
          __bfloat16_as_ushort(__float2bfloat16(f0.w))};
    o1 = {__bfloat16_as_ushort(__float2bfloat16(f1.x)),
          __bfloat16_as_ushort(__float2bfloat16(f1.y)),
          __bfloat16_as_ushort(__float2bfloat16(f1.z)),
          __bfloat16_as_ushort(__float2bfloat16(f1.w))};
  } else {
    o0 = {0, 0, 0, 0};
    o1 = {0, 0, 0, 0};
  }
  *(ushort4*)((unsigned short*)dst + idx8) = o0;
  *(ushort4*)((unsigned short*)dst + idx8 + 4) = o1;
}

// ---------------------------------------------------------------------------
// W[256][N] fp32 -> Bt[N][256] bf16 (tiny; naive is fine)
// ---------------------------------------------------------------------------
__global__ __launch_bounds__(256) void transpose_bf16(
    const float* __restrict__ W, __hip_bfloat16* __restrict__ Bt, int N) {
  const int o = blockIdx.x * 256 + threadIdx.x;  // grid = N blocks
  const int n = o >> 8, k = o & 255;
  Bt[o] = __float2bfloat16(W[(size_t)k * N + n]);
}

// ---------------------------------------------------------------------------
// MFMA bf16 GEMM: C[M,N] = A[M,256] @ B[256,N] + bias.
// A: bf16 row-major [M][256]; Bt: bf16 col-major [N][256].
// Block 256 thr = 4 waves, tile 128x128, BK=32, global_load_lds width 16.
// OUT_MODE: 0 = fp32 row-major, 1 = bf16 row-major, 2 = bf16 value_h scatter.
// ---------------------------------------------------------------------------
template <int OUT_MODE>
__global__ __launch_bounds__(256) void gemm_mfma(
    const __hip_bfloat16* __restrict__ A, const __hip_bfloat16* __restrict__ Bt,
    const float* __restrict__ bias, void* __restrict__ Cout, int N,
    int M_valid) {
  __shared__ __hip_bfloat16 As[128 * 32];  // [m][k] 64 B/row (no pad: lds-dma)
  __shared__ __hip_bfloat16 Bs[128 * 32];  // [n][k]

  const int tid = threadIdx.x;
  const int wv = tid >> 6;
  const int lane = tid & 63;
  const int quad = lane >> 4;
  const int l16 = lane & 15;
  const int bm = blockIdx.y * 128;
  const int bn = blockIdx.x * 128;
  const int rw = (wv & 1) * 64;   // wave's row offset in tile
  const int cw = (wv >> 1) * 64;  // wave's col offset in tile

  const __hip_bfloat16* gA = A + (size_t)(bm + (tid >> 2)) * 256 + (tid & 3) * 8;
  const __hip_bfloat16* gB = Bt + (size_t)(bn + (tid >> 2)) * 256 + (tid & 3) * 8;
  char* ldsA0 = (char*)As + wv * 1024;
  char* ldsB0 = (char*)Bs + wv * 1024;

  f32x4 acc[4][4] = {};

#pragma unroll 1
  for (int k0 = 0; k0 < 256; k0 += 32) {
    __syncthreads();  // all waves done reading LDS before overwrite
    gl_lds16(gA + k0, ldsA0);
    gl_lds16(gA + 64 * 256 + k0, ldsA0 + 4096);
    gl_lds16(gB + k0, ldsB0);
    gl_lds16(gB + 64 * 256 + k0, ldsB0 + 4096);
    __syncthreads();  // vmcnt(0) drain: tiles resident

    bf16x8 af[4], bfr[4];
#pragma unroll
    for (int t = 0; t < 4; ++t) {
      af[t] = *(const bf16x8*)(As + (rw + t * 16 + l16) * 32 + quad * 8);
      bfr[t] = *(const bf16x8*)(Bs + (cw + t * 16 + l16) * 32 + quad * 8);
    }
#pragma unroll
    for (int i = 0; i < 4; ++i)
#pragma unroll
      for (int j = 0; j < 4; ++j)
        acc[i][j] = __builtin_amdgcn_mfma_f32_16x16x32_bf16(af[i], bfr[j],
                                                            acc[i][j], 0, 0, 0);
  }

  // Epilogue. C/D layout: col = lane&15, row = quad*4 + reg.
#pragma unroll
  for (int j = 0; j < 4; ++j) {
    const int col = bn + cw + j * 16 + l16;
    const float bb = bias[col];
#pragma unroll
    for (int i = 0; i < 4; ++i) {
#pragma unroll
      for (int r = 0; r < 4; ++r) {
        const int row = bm + rw + i * 16 + quad * 4 + r;
        const float v = acc[i][j][r] + bb;
        if (OUT_MODE == 0) {
          ((float*)Cout)[(size_t)row * N + col] = v;
        } else if (OUT_MODE == 1) {
          ((__hip_bfloat16*)Cout)[(size_t)row * N + col] = __float2bfloat16(v);
        } else {
          if (row < M_valid) {
            const int b = row / LEN_IN;
            const int pix = row - b * LEN_IN;
            const int h = col >> 5, ch = col & 31;
            ((__hip_bfloat16*)Cout)[(((size_t)(b * 8 + h) * LEN_IN + pix) << 5) +
                                    ch] = __float2bfloat16(v);
          }
        }
      }
    }
  }
}

// ---------------------------------------------------------------------------
// Sampler v4: 2 queries per 256-thread block.
// Phase 1 (all 256 lanes): lane = (sub-query, point). Fused softmax over
// 16-groups via shfl; emits 4 fully-resolved taps per point into LDS as
// {byte_offset, weight} pairs (clamping + validity folded in; no selects
// survive into phase 2).
// Phase 2: lane = (sub-query sq, head h, ch-group cg of 8ch, tap). Per point:
// 1 ds_read_b64 (imm offset, bank-padded) + 1 v_add + 1 global_load_dwordx4
// (16 B = 8 channels, saddr form: uniform base + 32-bit voffset) + 8 FMA.
// Tap reduce via quad shfl_xor; tap==0 lane stores 16 B bf16.
// ---------------------------------------------------------------------------
__global__ __launch_bounds__(256) void msda_sample4(
    const float* __restrict__ refp,            // (NQ, 8)
    const float* __restrict__ logits,          // (NQ, 128) fp32 raw
    const __hip_bfloat16* __restrict__ offb,   // (NQ, 256) bf16
    const __hip_bfloat16* __restrict__ vh,     // (NB*8, LEN_IN, 32)
    __hip_bfloat16* __restrict__ mid) {        // (NQ, 256) bf16
  const int q0 = blockIdx.x * 2;
  const int tid = threadIdx.x;

  // [sq][head][point-in-head(16, padded to 17)][tap] = {byte_off, weight_bits}
  // pad 17: head stride 544 B -> bank offset 8 per head -> phase-2 reads
  // (4 heads x 4 taps per wave) spread across all 32 banks, conflict-free.
  __shared__ int2 s_d[2][8][17][4];

  {
    const int sq = tid >> 7;
    const int t = tid & 127;  // (h*NLV + l)*NPT + p  == h*16 + l*4 + p
    const int qg = q0 + sq;
    const int l = (t >> 2) & 3;
    constexpr int Hs[4] = {92, 46, 23, 12};
    constexpr int Ws_[4] = {160, 80, 40, 20};
    constexpr int St[4] = {0, 14720, 18400, 19320};
    const int Hl = Hs[l], Wl = Ws_[l];

    // fused softmax over 16-groups (xor masks 1,2,4,8 stay in-group)
    const float lg = logits[(size_t)qg * 128 + t];
    float mx = lg;
#pragma unroll
    for (int d = 1; d < 16; d <<= 1) mx = fmaxf(mx, __shfl_xor(mx, d));
    const float e = expf(lg - mx);
    float sm = e;
#pragma unroll
    for (int d = 1; d < 16; d <<= 1) sm += __shfl_xor(sm, d);
    const float w = e / sm;

    const float rx = refp[(size_t)qg * 8 + 2 * l];
    const float ry = refp[(size_t)qg * 8 + 2 * l + 1];
    const unsigned uo = *(const unsigned*)(offb + (size_t)qg * 256 + 2 * t);
    const float ox = bflo(uo), oy = bfhi(uo);

    const float x = rx * (float)Wl + ox - 0.5f;
    const float y = ry * (float)Hl + oy - 0.5f;
    const float xf = floorf(x), yf = floorf(y);
    const float wx = x - xf, wy = y - yf;
    const int x0 = (int)xf, y0 = (int)yf;
    const int x1 = x0 + 1, y1 = y0 + 1;
    const bool vx0 = (x0 >= 0) & (x0 < Wl), vx1 = (x1 >= 0) & (x1 < Wl);
    const bool vy0 = (y0 >= 0) & (y0 < Hl), vy1 = (y1 >= 0) & (y1 < Hl);
    const int cx0 = min(max(x0, 0), Wl - 1), cx1 = min(max(x1, 0), Wl - 1);
    const int cy0 = min(max(y0, 0), Hl - 1), cy1 = min(max(y1, 0), Hl - 1);

    const int o00 = (St[l] + cy0 * Wl + cx0) * 64;  // 64 B per pixel
    const int o01 = (St[l] + cy1 * Wl + cx0) * 64;
    const int dx = (cx1 - cx0) * 64;                // 0 or 64

    int2* dd = s_d[sq][t >> 4][t & 15];
    dd[0] = make_int2(o00,      __float_as_int((vx0 & vy0) ? w * (1.f - wx) * (1.f - wy) : 0.f));
    dd[1] = make_int2(o00 + dx, __float_as_int((vx1 & vy0) ? w * wx * (1.f - wy) : 0.f));
    dd[2] = make_int2(o01,      __float_as_int((vx0 & vy1) ? w * (1.f - wx) * wy : 0.f));
    dd[3] = make_int2(o01 + dx, __float_as_int((vx1 & vy1) ? w * wx * wy : 0.f));
  }
  __syncthreads();

  const int tap = tid & 3;
  const int cg = (tid >> 2) & 3;   // 4 channel-groups x 8 ch = 32 ch
  const int h = (tid >> 4) & 7;
  const int sq = tid >> 7;
  const int qg = q0 + sq;
  const int bq = q0 >> 13;         // batch; same for both sub-queries (q0 even)

  // uniform base (block-scalar) + 32-bit unsigned voffset -> saddr loads
  const char* vbase = (const char*)vh + (size_t)bq * (8ULL * LEN_IN * 64);
  const int voff0 = h * (LEN_IN * 64) + cg * 16;
  const int2* sd = &s_d[sq][h][0][tap];

  float a[8] = {};
#pragma unroll
  for (int pt = 0; pt < 16; ++pt) {
    const int2 dw = sd[pt * 4];                 // ds_read_b64, imm offset pt*32
    const float w = __int_as_float(dw.y);
    const unsigned voff = (unsigned)(voff0 + dw.x);
    const uint4 u = *(const uint4*)(vbase + voff);
    a[0] += w * bflo(u.x); a[1] += w * bfhi(u.x);
    a[2] += w * bflo(u.y); a[3] += w * bfhi(u.y);
    a[4] += w * bflo(u.z); a[5] += w * bfhi(u.z);
    a[6] += w * bflo(u.w); a[7] += w * bfhi(u.w);
  }

  // reduce over the 4 tap lanes (quad-local -> DPP adds)
#pragma unroll
  for (int i = 0; i < 8; ++i) a[i] += __shfl_xor(a[i], 1);
#pragma unroll
  for (int i = 0; i < 8; ++i) a[i] += __shfl_xor(a[i], 2);

  if (tap == 0) {
    unsigned short* mp =
        (unsigned short*)mid + (size_t)qg * 256 + h * 32 + cg * 8;
    int4 o;
    o.x = (int)((unsigned)__bfloat16_as_ushort(__float2bfloat16(a[0])) |
                ((unsigned)__bfloat16_as_ushort(__float2bfloat16(a[1])) << 16));
    o.y = (int)((unsigned)__bfloat16_as_ushort(__float2bfloat16(a[2])) |
                ((unsigned)__bfloat16_as_ushort(__float2bfloat16(a[3])) << 16));
    o.z = (int)((unsigned)__bfloat16_as_ushort(__float2bfloat16(a[4])) |
                ((unsigned)__bfloat16_as_ushort(__float2bfloat16(a[5])) << 16));
    o.w = (int)((unsigned)__bfloat16_as_ushort(__float2bfloat16(a[6])) |
                ((unsigned)__bfloat16_as_ushort(__float2bfloat16(a[7])) << 16));
    *(int4*)mp = o;
  }
}

// ---------------------------------------------------------------------------
// Launch
// ---------------------------------------------------------------------------
extern "C" void kernel_launch(void* const* d_in, const int* in_sizes, int n_in,
                              void* d_out, int out_size, void* d_ws,
                              size_t ws_size, hipStream_t stream) {
  const float* query = (const float*)d_in[0];
  const float* refp = (const float*)d_in[1];
  const float* inflat = (const float*)d_in[2];
  const float* W_off = (const float*)d_in[5];
  const float* b_off = (const float*)d_in[6];
  const float* W_attn = (const float*)d_in[7];
  const float* b_attn = (const float*)d_in[8];
  const float* W_val = (const float*)d_in[9];
  const float* b_val = (const float*)d_in[10];
  const float* W_out = (const float*)d_in[11];
  const float* b_out = (const float*)d_in[12];
  float* out = (float*)d_out;

  // Workspace layout (bytes):
  char* ws = (char*)d_ws;
  __hip_bfloat16* Abuf = (__hip_bfloat16*)(ws);                  // [156544][256] bf16
  __hip_bfloat16* Qbuf = (__hip_bfloat16*)(ws + 80150528ULL);    // [65536][256]
  __hip_bfloat16* vh = (__hip_bfloat16*)(ws + 113704960ULL);     // [64][19560][32]
  float* logits = (float*)(ws + 193822720ULL);                   // [65536][128] f32
  __hip_bfloat16* offb = (__hip_bfloat16*)(ws + 227377152ULL);   // [65536][256]
  __hip_bfloat16* mid = (__hip_bfloat16*)(ws + 260931584ULL);    // [65536][256]
  __hip_bfloat16* Btv = (__hip_bfloat16*)(ws + 294486016ULL);    // [256][256]
  __hip_bfloat16* Bta = (__hip_bfloat16*)(ws + 294617088ULL);    // [128][256]
  __hip_bfloat16* Bto = (__hip_bfloat16*)(ws + 294682624ULL);    // [256][256]
  __hip_bfloat16* Btw = (__hip_bfloat16*)(ws + 294813696ULL);    // [256][256]
  // total 294,944,768 B

  // conversions (independent)
  convert_bf16_pad<<<(MVP * 256 / 8) / 256, 256, 0, stream>>>(
      inflat, Abuf, (long)MV * 256);
  convert_bf16_pad<<<(NQ * 256 / 8) / 256, 256, 0, stream>>>(
      query, Qbuf, (long)NQ * 256);
  transpose_bf16<<<256, 256, 0, stream>>>(W_val, Btv, 256);
  transpose_bf16<<<128, 256, 0, stream>>>(W_attn, Bta, 128);
  transpose_bf16<<<256, 256, 0, stream>>>(W_off, Bto, 256);
  transpose_bf16<<<256, 256, 0, stream>>>(W_out, Btw, 256);

  // 1. value = inflat @ W_val + b_val -> head-major bf16 value_h
  gemm_mfma<2><<<dim3(2, MVP / 128), 256, 0, stream>>>(Abuf, Btv, b_val, vh,
                                                       256, MV);
  // 2. attn logits = query @ W_attn + b_attn -> fp32 (softmax fused in sampler)
  gemm_mfma<0><<<dim3(1, NQ / 128), 256, 0, stream>>>(Qbuf, Bta, b_attn,
                                                      logits, 128, NQ);
  // 3. offsets = query @ W_off + b_off -> bf16
  gemm_mfma<1><<<dim3(2, NQ / 128), 256, 0, stream>>>(Qbuf, Bto, b_off, offb,
                                                      256, NQ);
  // 4. sampling (softmax fused, 2 queries/block) -> mid bf16
  msda_sample4<<<NQ / 2, 256, 0, stream>>>(refp, logits, offb, vh, mid);
  // 5. out = mid @ W_out + b_out -> fp32 d_out
  gemm_mfma<0><<<dim3(2, NQ / 128), 256, 0, stream>>>(mid, Btw, b_out, out,
                                                      256, NQ);
}

// Round 2
// 575.039 us; speedup vs baseline: 1.2296x; 1.0381x over previous
//
#include <hip/hip_runtime.h>
#include <hip/hip_bf16.h>
#include <cstddef>
#include <cstdint>

#define NB 8
#define LQ 8192
#define DMODEL 256
#define NHD 8
#define NLV 4
#define NPT 4
#define LEN_IN 19560          // 92*160 + 46*80 + 23*40 + 12*20
#define NQ (NB * LQ)          // 65536
#define MV (NB * LEN_IN)      // 156480
#define MVP 156544            // MV padded to multiple of 128 (1223*128)

using bf16x8 = __attribute__((ext_vector_type(8))) short;
using f32x4  = __attribute__((ext_vector_type(4))) float;

typedef const __attribute__((address_space(1))) void* gas_ptr;
typedef __attribute__((address_space(3))) void* las_ptr;

__device__ __forceinline__ void gl_lds16(const void* g, void* l) {
  __builtin_amdgcn_global_load_lds((gas_ptr)g, (las_ptr)l, 16, 0, 0);
}
__device__ __forceinline__ float bflo(unsigned u) {
  union { unsigned i; float f; } c; c.i = u << 16; return c.f;
}
__device__ __forceinline__ float bfhi(unsigned u) {
  union { unsigned i; float f; } c; c.i = u & 0xffff0000u; return c.f;
}
__device__ __forceinline__ bf16x8 pack8(float4 a, float4 b) {
  bf16x8 o;
  o[0] = (short)__bfloat16_as_ushort(__float2bfloat16(a.x));
  o[1] = (short)__bfloat16_as_ushort(__float2bfloat16(a.y));
  o[2] = (short)__bfloat16_as_ushort(__float2bfloat16(a.z));
  o[3] = (short)__bfloat16_as_ushort(__float2bfloat16(a.w));
  o[4] = (short)__bfloat16_as_ushort(__float2bfloat16(b.x));
  o[5] = (short)__bfloat16_as_ushort(__float2bfloat16(b.y));
  o[6] = (short)__bfloat16_as_ushort(__float2bfloat16(b.z));
  o[7] = (short)__bfloat16_as_ushort(__float2bfloat16(b.w));
  return o;
}

// ---------------------------------------------------------------------------
// W[256][N] fp32 -> Bt[N][256] bf16 (tiny; naive is fine)
// ---------------------------------------------------------------------------
__global__ __launch_bounds__(256) void transpose_bf16(
    const float* __restrict__ W, __hip_bfloat16* __restrict__ Bt, int N) {
  const int o = blockIdx.x * 256 + threadIdx.x;  // grid = N blocks
  const int n = o >> 8, k = o & 255;
  Bt[o] = __float2bfloat16(W[(size_t)k * N + n]);
}

// ---------------------------------------------------------------------------
// MFMA bf16 GEMM: C[M,N] = A[M,256] @ B[256,N] + bias.
// A: fp32 row-major (A_F32=1, reg-staged + cvt) or bf16 row-major (lds-dma).
// Bt: bf16 col-major [N][256]. Block 256 thr = 4 waves, tile 128x128, BK=32.
// OUT_MODE: 0 = fp32 row-major (bias)
//           2 = bf16 value_h scatter (bias)
//           3 = fused split: bn==0 -> fp32 logits N=128 (bias);
//               bn>=128   -> bf16 offb N=256 at col-128 (bias2)
// ---------------------------------------------------------------------------
template <int OUT_MODE, int A_F32>
__global__ __launch_bounds__(256) void gemm_mfma(
    const void* __restrict__ Av, const __hip_bfloat16* __restrict__ Bt,
    const float* __restrict__ bias, const float* __restrict__ bias2,
    void* __restrict__ Cout, void* __restrict__ Cout2, int N, int M_valid) {
  __shared__ __hip_bfloat16 As[128 * 32];  // [m][k] 64 B/row
  __shared__ __hip_bfloat16 Bs[128 * 32];  // [n][k]

  const int tid = threadIdx.x;
  const int wv = tid >> 6;
  const int lane = tid & 63;
  const int quad = lane >> 4;
  const int l16 = lane & 15;
  const int bm = blockIdx.y * 128;
  const int bn = blockIdx.x * 128;
  const int rw = (wv & 1) * 64;   // wave's row offset in tile
  const int cw = (wv >> 1) * 64;  // wave's col offset in tile

  // B staging (lds-dma): slot = tid / tid+256; n = slot>>2, k8 = (slot&3)*8
  const __hip_bfloat16* gB = Bt + (size_t)(bn + (tid >> 2)) * 256 + (tid & 3) * 8;
  char* ldsB0 = (char*)Bs + wv * 1024;

  // A staging
  const __hip_bfloat16* gA16 = nullptr;
  const float* gA32 = nullptr;
  char* ldsA0 = (char*)As + wv * 1024;
  __hip_bfloat16* dA = nullptr;
  bool okA = true;
  if (A_F32) {
    const int r = tid >> 1, half = tid & 1;  // thread stages half a row (16 f)
    okA = (bm + r) < M_valid;
    gA32 = (const float*)Av + (size_t)(bm + r) * 256 + half * 16;
    dA = As + r * 32 + half * 16;
  } else {
    gA16 = (const __hip_bfloat16*)Av + (size_t)(bm + (tid >> 2)) * 256 +
           (tid & 3) * 8;
  }

  f32x4 acc[4][4] = {};

#pragma unroll 1
  for (int k0 = 0; k0 < 256; k0 += 32) {
    float4 f0, f1, f2, f3;
    if (A_F32) {
      if (okA) {
        f0 = *(const float4*)(gA32 + k0);
        f1 = *(const float4*)(gA32 + k0 + 4);
        f2 = *(const float4*)(gA32 + k0 + 8);
        f3 = *(const float4*)(gA32 + k0 + 12);
      } else {
        f0 = f1 = f2 = f3 = make_float4(0.f, 0.f, 0.f, 0.f);
      }
    }
    __syncthreads();  // all waves done reading LDS before overwrite
    gl_lds16(gB + k0, ldsB0);
    gl_lds16(gB + 64 * 256 + k0, ldsB0 + 4096);
    if (A_F32) {
      *(bf16x8*)dA = pack8(f0, f1);
      *(bf16x8*)(dA + 8) = pack8(f2, f3);
    } else {
      gl_lds16(gA16 + k0, ldsA0);
      gl_lds16(gA16 + 64 * 256 + k0, ldsA0 + 4096);
    }
    __syncthreads();  // vmcnt(0)+lgkmcnt(0) drain: tiles resident

    bf16x8 af[4], bfr[4];
#pragma unroll
    for (int t = 0; t < 4; ++t) {
      af[t] = *(const bf16x8*)(As + (rw + t * 16 + l16) * 32 + quad * 8);
      bfr[t] = *(const bf16x8*)(Bs + (cw + t * 16 + l16) * 32 + quad * 8);
    }
#pragma unroll
    for (int i = 0; i < 4; ++i)
#pragma unroll
      for (int j = 0; j < 4; ++j)
        acc[i][j] = __builtin_amdgcn_mfma_f32_16x16x32_bf16(af[i], bfr[j],
                                                            acc[i][j], 0, 0, 0);
  }

  // Epilogue. C/D layout: col = lane&15, row = quad*4 + reg.
#pragma unroll
  for (int j = 0; j < 4; ++j) {
    const int col = bn + cw + j * 16 + l16;
    float bb;
    if (OUT_MODE == 3)
      bb = (bn == 0) ? bias[col] : bias2[col - 128];
    else
      bb = bias[col];
#pragma unroll
    for (int i = 0; i < 4; ++i) {
#pragma unroll
      for (int r = 0; r < 4; ++r) {
        const int row = bm + rw + i * 16 + quad * 4 + r;
        const float v = acc[i][j][r] + bb;
        if (OUT_MODE == 0) {
          ((float*)Cout)[(size_t)row * N + col] = v;
        } else if (OUT_MODE == 2) {
          if (row < M_valid) {
            const int b = row / LEN_IN;
            const int pix = row - b * LEN_IN;
            const int h = col >> 5, ch = col & 31;
            ((__hip_bfloat16*)Cout)[(((size_t)(b * 8 + h) * LEN_IN + pix) << 5) +
                                    ch] = __float2bfloat16(v);
          }
        } else {  // OUT_MODE == 3
          if (bn == 0) {
            ((float*)Cout)[(size_t)row * 128 + col] = v;
          } else {
            ((__hip_bfloat16*)Cout2)[(size_t)row * 256 + (col - 128)] =
                __float2bfloat16(v);
          }
        }
      }
    }
  }
}

// ---------------------------------------------------------------------------
// Sampler v4: 2 queries per 256-thread block. (unchanged from round 1)
// ---------------------------------------------------------------------------
__global__ __launch_bounds__(256) void msda_sample4(
    const float* __restrict__ refp,            // (NQ, 8)
    const float* __restrict__ logits,          // (NQ, 128) fp32 raw
    const __hip_bfloat16* __restrict__ offb,   // (NQ, 256) bf16
    const __hip_bfloat16* __restrict__ vh,     // (NB*8, LEN_IN, 32)
    __hip_bfloat16* __restrict__ mid) {        // (NQ, 256) bf16
  const int q0 = blockIdx.x * 2;
  const int tid = threadIdx.x;

  __shared__ int2 s_d[2][8][17][4];

  {
    const int sq = tid >> 7;
    const int t = tid & 127;  // (h*NLV + l)*NPT + p  == h*16 + l*4 + p
    const int qg = q0 + sq;
    const int l = (t >> 2) & 3;
    constexpr int Hs[4] = {92, 46, 23, 12};
    constexpr int Ws_[4] = {160, 80, 40, 20};
    constexpr int St[4] = {0, 14720, 18400, 19320};
    const int Hl = Hs[l], Wl = Ws_[l];

    const float lg = logits[(size_t)qg * 128 + t];
    float mx = lg;
#pragma unroll
    for (int d = 1; d < 16; d <<= 1) mx = fmaxf(mx, __shfl_xor(mx, d));
    const float e = expf(lg - mx);
    float sm = e;
#pragma unroll
    for (int d = 1; d < 16; d <<= 1) sm += __shfl_xor(sm, d);
    const float w = e / sm;

    const float rx = refp[(size_t)qg * 8 + 2 * l];
    const float ry = refp[(size_t)qg * 8 + 2 * l + 1];
    const unsigned uo = *(const unsigned*)(offb + (size_t)qg * 256 + 2 * t);
    const float ox = bflo(uo), oy = bfhi(uo);

    const float x = rx * (float)Wl + ox - 0.5f;
    const float y = ry * (float)Hl + oy - 0.5f;
    const float xf = floorf(x), yf = floorf(y);
    const float wx = x - xf, wy = y - yf;
    const int x0 = (int)xf, y0 = (int)yf;
    const int x1 = x0 + 1, y1 = y0 + 1;
    const bool vx0 = (x0 >= 0) & (x0 < Wl), vx1 = (x1 >= 0) & (x1 < Wl);
    const bool vy0 = (y0 >= 0) & (y0 < Hl), vy1 = (y1 >= 0) & (y1 < Hl);
    const int cx0 = min(max(x0, 0), Wl - 1), cx1 = min(max(x1, 0), Wl - 1);
    const int cy0 = min(max(y0, 0), Hl - 1), cy1 = min(max(y1, 0), Hl - 1);

    const int o00 = (St[l] + cy0 * Wl + cx0) * 64;  // 64 B per pixel
    const int o01 = (St[l] + cy1 * Wl + cx0) * 64;
    const int dx = (cx1 - cx0) * 64;                // 0 or 64

    int2* dd = s_d[sq][t >> 4][t & 15];
    dd[0] = make_int2(o00,      __float_as_int((vx0 & vy0) ? w * (1.f - wx) * (1.f - wy) : 0.f));
    dd[1] = make_int2(o00 + dx, __float_as_int((vx1 & vy0) ? w * wx * (1.f - wy) : 0.f));
    dd[2] = make_int2(o01,      __float_as_int((vx0 & vy1) ? w * (1.f - wx) * wy : 0.f));
    dd[3] = make_int2(o01 + dx, __float_as_int((vx1 & vy1) ? w * wx * wy : 0.f));
  }
  __syncthreads();

  const int tap = tid & 3;
  const int cg = (tid >> 2) & 3;   // 4 channel-groups x 8 ch = 32 ch
  const int h = (tid >> 4) & 7;
  const int sq = tid >> 7;
  const int qg = q0 + sq;
  const int bq = q0 >> 13;         // batch; same for both sub-queries

  const char* vbase = (const char*)vh + (size_t)bq * (8ULL * LEN_IN * 64);
  const int voff0 = h * (LEN_IN * 64) + cg * 16;
  const int2* sd = &s_d[sq][h][0][tap];

  float a[8] = {};
#pragma unroll
  for (int pt = 0; pt < 16; ++pt) {
    const int2 dw = sd[pt * 4];                 // ds_read_b64, imm offset
    const float w = __int_as_float(dw.y);
    const unsigned voff = (unsigned)(voff0 + dw.x);
    const uint4 u = *(const uint4*)(vbase + voff);
    a[0] += w * bflo(u.x); a[1] += w * bfhi(u.x);
    a[2] += w * bflo(u.y); a[3] += w * bfhi(u.y);
    a[4] += w * bflo(u.z); a[5] += w * bfhi(u.z);
    a[6] += w * bflo(u.w); a[7] += w * bfhi(u.w);
  }

#pragma unroll
  for (int i = 0; i < 8; ++i) a[i] += __shfl_xor(a[i], 1);
#pragma unroll
  for (int i = 0; i < 8; ++i) a[i] += __shfl_xor(a[i], 2);

  if (tap == 0) {
    unsigned short* mp =
        (unsigned short*)mid + (size_t)qg * 256 + h * 32 + cg * 8;
    int4 o;
    o.x = (int)((unsigned)__bfloat16_as_ushort(__float2bfloat16(a[0])) |
                ((unsigned)__bfloat16_as_ushort(__float2bfloat16(a[1])) << 16));
    o.y = (int)((unsigned)__bfloat16_as_ushort(__float2bfloat16(a[2])) |
                ((unsigned)__bfloat16_as_ushort(__float2bfloat16(a[3])) << 16));
    o.z = (int)((unsigned)__bfloat16_as_ushort(__float2bfloat16(a[4])) |
                ((unsigned)__bfloat16_as_ushort(__float2bfloat16(a[5])) << 16));
    o.w = (int)((unsigned)__bfloat16_as_ushort(__float2bfloat16(a[6])) |
                ((unsigned)__bfloat16_as_ushort(__float2bfloat16(a[7])) << 16));
    *(int4*)mp = o;
  }
}

// ---------------------------------------------------------------------------
// Launch
// ---------------------------------------------------------------------------
extern "C" void kernel_launch(void* const* d_in, const int* in_sizes, int n_in,
                              void* d_out, int out_size, void* d_ws,
                              size_t ws_size, hipStream_t stream) {
  const float* query = (const float*)d_in[0];
  const float* refp = (const float*)d_in[1];
  const float* inflat = (const float*)d_in[2];
  const float* W_off = (const float*)d_in[5];
  const float* b_off = (const float*)d_in[6];
  const float* W_attn = (const float*)d_in[7];
  const float* b_attn = (const float*)d_in[8];
  const float* W_val = (const float*)d_in[9];
  const float* b_val = (const float*)d_in[10];
  const float* W_out = (const float*)d_in[11];
  const float* b_out = (const float*)d_in[12];
  float* out = (float*)d_out;

  // Workspace layout (bytes):
  char* ws = (char*)d_ws;
  __hip_bfloat16* vh = (__hip_bfloat16*)(ws);                    // [64][19560][32]
  float* logits = (float*)(ws + 80117760ULL);                    // [65536][128] f32
  __hip_bfloat16* offb = (__hip_bfloat16*)(ws + 113672192ULL);   // [65536][256]
  __hip_bfloat16* mid = (__hip_bfloat16*)(ws + 147226624ULL);    // [65536][256]
  __hip_bfloat16* Btv = (__hip_bfloat16*)(ws + 180781056ULL);    // [256][256]
  __hip_bfloat16* Btc = (__hip_bfloat16*)(ws + 180912128ULL);    // [384][256] attn||off
  __hip_bfloat16* Btw = (__hip_bfloat16*)(ws + 181108736ULL);    // [256][256]
  // total 181,239,808 B

  // weight transposes (tiny)
  transpose_bf16<<<256, 256, 0, stream>>>(W_val, Btv, 256);
  transpose_bf16<<<128, 256, 0, stream>>>(W_attn, Btc, 128);
  transpose_bf16<<<256, 256, 0, stream>>>(W_off, Btc + 128 * 256, 256);
  transpose_bf16<<<256, 256, 0, stream>>>(W_out, Btw, 256);

  // 1. value = inflat @ W_val + b_val -> head-major bf16 value_h  (A fp32)
  gemm_mfma<2, 1><<<dim3(2, MVP / 128), 256, 0, stream>>>(
      inflat, Btv, b_val, nullptr, vh, nullptr, 256, MV);
  // 2+3 fused: [logits | offsets] = query @ [W_attn | W_off]  (A fp32)
  gemm_mfma<3, 1><<<dim3(3, NQ / 128), 256, 0, stream>>>(
      query, Btc, b_attn, b_off, logits, offb, 384, NQ);
  // 4. sampling (softmax fused, 2 queries/block) -> mid bf16
  msda_sample4<<<NQ / 2, 256, 0, stream>>>(refp, logits, offb, vh, mid);
  // 5. out = mid @ W_out + b_out -> fp32 d_out  (A bf16, lds-dma)
  gemm_mfma<0, 0><<<dim3(2, NQ / 128), 256, 0, stream>>>(
      mid, Btw, b_out, nullptr, out, nullptr, 256, NQ);
}